// Round 13
// baseline (368.493 us; speedup 1.0000x reference)
//
#include <hip/hip_runtime.h>

#define NN 80000     // nodes
#define NE 800000    // edges
#define EH 400000    // first half -> in_w
#define NR 400       // relations
#define DD 256       // feature dim
#define FD 256       // freq row: col0=bin0.re, col1=bin128.re, 2k/2k+1=bin k
#define KP 768       // GEMM K = 256*3 (in | out | self), = 12*64 exactly
#define NB 160000    // sort buckets: dir*NN + dst
#define NCH 157      // ceil(NB/1024) scan chunks
#define MT 80400     // total DFT rows (x + rel)
#define PI2 6.283185307179586f

typedef unsigned short u16;
typedef __attribute__((ext_vector_type(8))) short bf16x8;
typedef __attribute__((ext_vector_type(4))) float f32x4;
typedef __attribute__((ext_vector_type(2))) float f32x2;

static __device__ __forceinline__ float bu2f(u16 u) {
  return __uint_as_float(((unsigned int)u) << 16);
}
static __device__ __forceinline__ u16 f2bu(float f) {
  unsigned int x = __float_as_uint(f);
  x += 0x7fffu + ((x >> 16) & 1u);   // RNE
  return (u16)(x >> 16);
}
static __device__ __forceinline__ unsigned int pk2(float a, float b) {
  return (unsigned int)f2bu(a) | ((unsigned int)f2bu(b) << 16);
}
// async global->LDS 16B: lds dest = wave-uniform base + lane*16
static __device__ __forceinline__ void gload16(const void* g, void* l) {
  __builtin_amdgcn_global_load_lds(
      (const __attribute__((address_space(1))) unsigned int*)g,
      (__attribute__((address_space(3))) unsigned int*)l, 16, 0, 0);
}

// merged: blocks 0..255 Ft; 256..767 Bt in/out; 768..1023 Bt self; 1024+ hist
__global__ void k_build(const float* __restrict__ in_w, const float* __restrict__ out_w,
                        const float* __restrict__ lr, const float* __restrict__ loop_w,
                        const int* __restrict__ edst, int* __restrict__ cnt,
                        u16* __restrict__ Ft, u16* __restrict__ Bt) {
  __shared__ float L[DD];
  int bb = blockIdx.x, c = threadIdx.x;
  if (bb >= 1024) {                    // histogram branch
    int e = (bb - 1024) * 256 + c;
    int key = edst[e] + ((e >= EH) ? NN : 0);
    atomicAdd(&cnt[key], 1);
    return;
  }
  if (bb < 256) {
    int row = bb, j = c;
    int k, im;
    if (row == 0)      { k = 0;   im = 0; }
    else if (row == 1) { k = 128; im = 0; }
    else               { k = row >> 1; im = row & 1; }
    int m = (j * k) & 255;
    float th = -PI2 * (float)m * (1.0f / 256.0f);
    Ft[row * 256 + j] = f2bu(im ? sinf(th) : cosf(th));
  } else if (bb < 768) {
    int t = bb - 256;                  // 0..511
    const float* W = (t < 256) ? in_w : out_w;
    int tp = t & 255;
    int k, im; float alpha;
    if (tp == 0)      { k = 0;   im = 0; alpha = 1.0f; }
    else if (tp == 1) { k = 128; im = 0; alpha = 1.0f; }
    else              { k = tp >> 1; im = tp & 1; alpha = 2.0f; }
    float scale = alpha * (1.0f / 768.0f);
    int m = (c * k) & 255;
    float th = -PI2 * (float)m * (1.0f / 256.0f);
    L[c] = im ? sinf(th) : cosf(th);
    __syncthreads();
    float acc = 0.0f;
    for (int j = 0; j < DD; ++j)
      acc += L[j] * W[(size_t)j * DD + c];
    Bt[(size_t)c * KP + t] = f2bu(scale * acc);
  } else {
    int j = bb - 768;                  // 0..255
    L[c] = lr[c];
    __syncthreads();
    float acc = 0.0f;
    for (int k2 = 0; k2 < DD; ++k2)
      acc += L[(j + k2) & 255] * loop_w[(size_t)k2 * DD + c];
    Bt[(size_t)c * KP + 512 + j] = f2bu(acc * (1.0f / 3.0f));
  }
}

// MFMA DFT, N-fused 128x256: XF = [x;rel] @ Ft^T -> xfh/rfh (bf16, 512B rows)
__global__ __launch_bounds__(512) void k_dft(
    const float* __restrict__ x, const float* __restrict__ rel,
    const u16* __restrict__ Ft, u16* __restrict__ xfh, u16* __restrict__ rfh,
    u16* __restrict__ Ap) {
  __shared__ u16 sA[2][128 * 64];
  __shared__ u16 sB[256 * 64];
  int tid = threadIdx.x;
  int w = tid >> 6, lane = tid & 63;
  int r0 = blockIdx.x * 128;
  int wm = (w & 1) * 64, wn = (w >> 1) * 64;
  int fr = lane & 15, fg = lane >> 4;

  int arow = tid >> 2;                 // 0..127
  int acg = (tid & 3) * 16;            // 16 f32 per thread
  int gr = r0 + arow;
  int grc = gr < MT ? gr : MT - 1;
  const float* asrc = (grc < NN) ? (x + (size_t)grc * DD)
                                 : (rel + (size_t)(grc - NN) * DD);
  bool doAp = (gr < NN);

  float4 a0_, a1_, a2_, a3_;
#define LOADA(kb) { const float* p_ = asrc + (kb) * 64 + acg;                     \
    a0_ = *(const float4*)(p_);     a1_ = *(const float4*)(p_ + 4);               \
    a2_ = *(const float4*)(p_ + 8); a3_ = *(const float4*)(p_ + 12); }

#define STGB(kb) { _Pragma("unroll") for (int q = 0; q < 4; ++q) {                \
    int s_ = w * 4 + q; int c_ = 8 * s_ + (lane >> 3);                            \
    int cb_ = (lane & 7) ^ (c_ & 7);                                              \
    gload16(Ft + (size_t)c_ * 256 + (kb) * 64 + cb_ * 8, sB + s_ * 512); } }

#define CVTA(kb, buf) {                                                           \
    uint4 c0_ = make_uint4(pk2(a0_.x, a0_.y), pk2(a0_.z, a0_.w),                  \
                           pk2(a1_.x, a1_.y), pk2(a1_.z, a1_.w));                 \
    uint4 c1_ = make_uint4(pk2(a2_.x, a2_.y), pk2(a2_.z, a2_.w),                  \
                           pk2(a3_.x, a3_.y), pk2(a3_.z, a3_.w));                 \
    int b0_ = (tid & 3) * 2;                                                      \
    *(uint4*)(sA[buf] + arow * 64 + ((b0_ ^ (arow & 7)) * 8)) = c0_;              \
    *(uint4*)(sA[buf] + arow * 64 + (((b0_ + 1) ^ (arow & 7)) * 8)) = c1_;        \
    if (doAp) { u16* ap_ = Ap + (size_t)gr * KP + 512 + (kb) * 64 + acg;          \
      *(uint4*)(ap_) = c0_; *(uint4*)(ap_ + 8) = c1_; } }

  f32x4 acc[4][4];
#pragma unroll
  for (int i = 0; i < 4; ++i)
#pragma unroll
    for (int j = 0; j < 4; ++j) acc[i][j] = (f32x4){0.f, 0.f, 0.f, 0.f};

  LOADA(0)
  STGB(0)
  CVTA(0, 0)
  LOADA(1)
  __syncthreads();
  for (int kb = 0; kb < 4; ++kb) {
    int cur = kb & 1;
#pragma unroll
    for (int ks = 0; ks < 2; ++ks) {
      bf16x8 af[4], bfr[4];
#pragma unroll
      for (int mt = 0; mt < 4; ++mt) {
        int r = wm + mt * 16 + fr;
        af[mt] = *(const bf16x8*)(sA[cur] + r * 64 + ((ks * 32 + fg * 8) ^ ((r & 7) * 8)));
      }
#pragma unroll
      for (int nt = 0; nt < 4; ++nt) {
        int c = wn + nt * 16 + fr;
        bfr[nt] = *(const bf16x8*)(sB + c * 64 + ((ks * 32 + fg * 8) ^ ((c & 7) * 8)));
      }
#pragma unroll
      for (int mt = 0; mt < 4; ++mt)
#pragma unroll
        for (int nt = 0; nt < 4; ++nt)
          acc[mt][nt] = __builtin_amdgcn_mfma_f32_16x16x32_bf16(af[mt], bfr[nt],
                                                                acc[mt][nt], 0, 0, 0);
    }
    __syncthreads();
    if (kb < 3) {
      STGB(kb + 1)
      CVTA(kb + 1, cur ^ 1)
      if (kb < 2) LOADA(kb + 2)
      __syncthreads();
    }
  }
#undef LOADA
#undef STGB
#undef CVTA

#pragma unroll
  for (int mt = 0; mt < 4; ++mt)
#pragma unroll
    for (int nt = 0; nt < 4; ++nt) {
      int cg = wn + nt * 16 + fr;
#pragma unroll
      for (int j = 0; j < 4; ++j) {
        int rg = r0 + wm + mt * 16 + fg * 4 + j;
        u16 val = f2bu(acc[mt][nt][j]);
        if (rg < NN)      xfh[(size_t)rg * FD + cg] = val;
        else if (rg < MT) rfh[(size_t)(rg - NN) * FD + cg] = val;
      }
    }
}

__global__ __launch_bounds__(256) void k_scan1(const int* __restrict__ cnt,
                                               int* __restrict__ base,
                                               int* __restrict__ chunkTot) {
  __shared__ int wsum[4];
  int t = threadIdx.x;
  int g0 = blockIdx.x * 1024 + t * 4;
  int v[4], ex[4], s = 0;
#pragma unroll
  for (int j = 0; j < 4; ++j) v[j] = (g0 + j < NB) ? cnt[g0 + j] : 0;
#pragma unroll
  for (int j = 0; j < 4; ++j) { ex[j] = s; s += v[j]; }
  int lane = t & 63, w = t >> 6;
  int inc = s;
  for (int off = 1; off < 64; off <<= 1) {
    int n = __shfl_up(inc, off);
    if (lane >= off) inc += n;
  }
  if (lane == 63) wsum[w] = inc;
  __syncthreads();
  int woff = 0;
  for (int i = 0; i < w; ++i) woff += wsum[i];
  int exth = woff + inc - s;
#pragma unroll
  for (int j = 0; j < 4; ++j)
    if (g0 + j < NB) base[g0 + j] = exth + ex[j];
  if (t == 255) chunkTot[blockIdx.x] = woff + inc;
}

__global__ __launch_bounds__(256) void k_scan2(const int* __restrict__ chunkTot,
                                               int* __restrict__ chunkOff) {
  __shared__ int wsum[4];
  int t = threadIdx.x;
  int v = (t < NCH) ? chunkTot[t] : 0;
  int lane = t & 63, w = t >> 6;
  int inc = v;
  for (int off = 1; off < 64; off <<= 1) {
    int n = __shfl_up(inc, off);
    if (lane >= off) inc += n;
  }
  if (lane == 63) wsum[w] = inc;
  __syncthreads();
  int woff = 0;
  for (int i = 0; i < w; ++i) woff += wsum[i];
  if (t < NCH) chunkOff[t] = woff + inc - v;
}

__global__ void k_scan3(int* __restrict__ base, const int* __restrict__ chunkOff,
                        int* __restrict__ cursor) {
  int i = blockIdx.x * 256 + threadIdx.x;
  if (i < NB) {
    int b = base[i] + chunkOff[i >> 10];
    base[i] = b;
    cursor[i] = b;
  }
  if (i == 0) base[NB] = NE;
}

// scatter packed 8B records: {src | typ<<17, norm_bits} -> sorted position
__global__ void k_scatter(const int* __restrict__ esrc, const int* __restrict__ edst,
                          const int* __restrict__ etyp, const float* __restrict__ enorm,
                          int* __restrict__ cursor, uint2* __restrict__ recs) {
  int e = blockIdx.x * 256 + threadIdx.x;
  int key = edst[e] + ((e >= EH) ? NN : 0);
  int pos = atomicAdd(&cursor[key], 1);
  recs[pos] = make_uint2((unsigned int)esrc[e] | ((unsigned int)etyp[e] << 17),
                         __float_as_uint(enorm[e]));
}

// one wave per bucket, PREDICATED-QUAD ILP-4: every edge (incl. tail) runs with
// 8 gathers in flight; pad slots clamp to recs[start] (L1/L2 hit) with nm=0.
// lane0 pair (cols 0,1) = two REAL bins: product is elementwise.
__global__ __launch_bounds__(256) void k_reduce(
    const u16* __restrict__ xfh, const u16* __restrict__ rfh,
    const uint2* __restrict__ recs, const int* __restrict__ base,
    u16* __restrict__ Ap) {
  int w = threadIdx.x >> 6, lane = threadIdx.x & 63;
  int b = blockIdx.x * 4 + w;
  int start = base[b], end = base[b + 1];
  bool l0 = (lane == 0);
  f32x2 a01 = (f32x2){0.f, 0.f}, a23 = (f32x2){0.f, 0.f};
  for (int p = start; p < end; p += 4) {
    ushort4 xv[4], rv[4];
    float nm[4];
#pragma unroll
    for (int u = 0; u < 4; ++u) {
      int idx = p + u;
      int mi = (idx < end) ? idx : start;
      uint2 rc = recs[mi];
      nm[u] = (idx < end) ? __uint_as_float(rc.y) : 0.0f;
      unsigned int s = rc.x & 0x1FFFFu, r = rc.x >> 17;
      xv[u] = *(const ushort4*)(xfh + (size_t)s * FD + 4 * lane);
      rv[u] = *(const ushort4*)(rfh + (size_t)r * FD + 4 * lane);
    }
#pragma unroll
    for (int u = 0; u < 4; ++u) {
      float xr0 = bu2f(xv[u].x), xi0 = bu2f(xv[u].y);
      float xr1 = bu2f(xv[u].z), xi1 = bu2f(xv[u].w);
      float rr0 = bu2f(rv[u].x), ri0 = bu2f(rv[u].y);
      float rr1 = bu2f(rv[u].z), ri1 = bu2f(rv[u].w);
      f32x2 tc = (f32x2){xr0, xr0} * (f32x2){rr0, ri0}
               + (f32x2){xi0, -xi0} * (f32x2){ri0, rr0};
      f32x2 te = (f32x2){xr0, xi0} * (f32x2){rr0, ri0};
      f32x2 t0 = l0 ? te : tc;
      a01 += t0 * nm[u];
      f32x2 t1 = (f32x2){xr1, xr1} * (f32x2){rr1, ri1}
               + (f32x2){xi1, -xi1} * (f32x2){ri1, rr1};
      a23 += t1 * nm[u];
    }
  }
  u16* tp = Ap + ((b < NN) ? (size_t)b * KP : (size_t)(b - NN) * KP + 256);
  *(unsigned int*)(tp + 4 * lane)     = pk2(a01.x, a01.y);
  *(unsigned int*)(tp + 4 * lane + 2) = pk2(a23.x, a23.y);
}

// MFMA GEMM, N-fused 128x256: doutb(bf16) = Apack[80000][768] x Bt^T + bias
__global__ __launch_bounds__(512) void k_mgemm(
    const u16* __restrict__ Ap, const u16* __restrict__ Bt,
    const float* __restrict__ bias, u16* __restrict__ doutb,
    float* __restrict__ sum1, float* __restrict__ sum2) {
  __shared__ u16 sA[2][128 * 64];
  __shared__ u16 sB[256 * 64];
  int tid = threadIdx.x;
  int w = tid >> 6, lane = tid & 63;
  int r0 = blockIdx.x * 128;
  int wm = (w & 1) * 64, wn = (w >> 1) * 64;
  int fr = lane & 15, fg = lane >> 4;

#define STGA(kb, buf) { _Pragma("unroll") for (int q = 0; q < 2; ++q) {           \
    int s_ = w * 2 + q; int r_ = 8 * s_ + (lane >> 3);                            \
    int cb_ = (lane & 7) ^ (r_ & 7);                                              \
    gload16(Ap + (size_t)(r0 + r_) * KP + (kb) * 64 + cb_ * 8,                    \
            sA[buf] + s_ * 512); } }

#define STGB(kb) { _Pragma("unroll") for (int q = 0; q < 4; ++q) {                \
    int s_ = w * 4 + q; int c_ = 8 * s_ + (lane >> 3);                            \
    int cb_ = (lane & 7) ^ (c_ & 7);                                              \
    gload16(Bt + (size_t)c_ * KP + (kb) * 64 + cb_ * 8, sB + s_ * 512); } }

  f32x4 acc[4][4];
#pragma unroll
  for (int i = 0; i < 4; ++i)
#pragma unroll
    for (int j = 0; j < 4; ++j) acc[i][j] = (f32x4){0.f, 0.f, 0.f, 0.f};

  STGA(0, 0)
  STGB(0)
  __syncthreads();
  for (int kb = 0; kb < 12; ++kb) {
    int cur = kb & 1;
    if (kb < 11) STGA(kb + 1, cur ^ 1)
#pragma unroll
    for (int ks = 0; ks < 2; ++ks) {
      bf16x8 af[4], bfr[4];
#pragma unroll
      for (int mt = 0; mt < 4; ++mt) {
        int r = wm + mt * 16 + fr;
        af[mt] = *(const bf16x8*)(sA[cur] + r * 64 + ((ks * 32 + fg * 8) ^ ((r & 7) * 8)));
      }
#pragma unroll
      for (int nt = 0; nt < 4; ++nt) {
        int c = wn + nt * 16 + fr;
        bfr[nt] = *(const bf16x8*)(sB + c * 64 + ((ks * 32 + fg * 8) ^ ((c & 7) * 8)));
      }
#pragma unroll
      for (int mt = 0; mt < 4; ++mt)
#pragma unroll
        for (int nt = 0; nt < 4; ++nt)
          acc[mt][nt] = __builtin_amdgcn_mfma_f32_16x16x32_bf16(af[mt], bfr[nt],
                                                                acc[mt][nt], 0, 0, 0);
    }
    __syncthreads();
    if (kb < 11) { STGB(kb + 1) __syncthreads(); }
  }
#undef STGA
#undef STGB

  float s1[4] = {0.f, 0.f, 0.f, 0.f}, s2[4] = {0.f, 0.f, 0.f, 0.f};
#pragma unroll
  for (int nt = 0; nt < 4; ++nt) {
    int cg = wn + nt * 16 + fr;
    float bv = bias[cg];
#pragma unroll
    for (int mt = 0; mt < 4; ++mt) {
#pragma unroll
      for (int j = 0; j < 4; ++j) {
        int rg = r0 + wm + mt * 16 + fg * 4 + j;
        float val = acc[mt][nt][j] + bv;
        doutb[(size_t)rg * DD + cg] = f2bu(val);
        s1[nt] += val;
        s2[nt] += val * val;
      }
    }
  }
#pragma unroll
  for (int nt = 0; nt < 4; ++nt) {
    s1[nt] += __shfl_xor(s1[nt], 16); s1[nt] += __shfl_xor(s1[nt], 32);
    s2[nt] += __shfl_xor(s2[nt], 16); s2[nt] += __shfl_xor(s2[nt], 32);
  }
  if (lane < 16) {
#pragma unroll
    for (int nt = 0; nt < 4; ++nt) {
      atomicAdd(&sum1[wn + nt * 16 + lane], s1[nt]);
      atomicAdd(&sum2[wn + nt * 16 + lane], s2[nt]);
    }
  }
}

// merged: blocks 0..2047 normalize (bf16 in, f32 out); 2048.. rel GEMV
__global__ __launch_bounds__(256) void k_norm(const u16* __restrict__ doutb,
                                              float* __restrict__ out,
                                              const float* __restrict__ sum1,
                                              const float* __restrict__ sum2,
                                              const float* __restrict__ rel,
                                              const float* __restrict__ wrel,
                                              float* __restrict__ out2) {
  __shared__ float R[DD];
  int bb = blockIdx.x;
  if (bb >= 2048) {                    // rel branch
    int r = bb - 2048, c = threadIdx.x;
    R[c] = rel[(size_t)r * DD + c];
    __syncthreads();
    float acc = 0.0f;
    for (int j = 0; j < DD; ++j)
      acc += R[j] * wrel[(size_t)j * DD + c];
    out2[(size_t)r * DD + c] = acc;
    return;
  }
  size_t tid0 = (size_t)bb * 256 + threadIdx.x;
  int c0 = (int)((tid0 * 4) & 255);
  float m[4], rs[4];
#pragma unroll
  for (int j = 0; j < 4; ++j) {
    float mm = sum1[c0 + j] * (1.0f / (float)NN);
    float var = sum2[c0 + j] * (1.0f / (float)NN) - mm * mm;
    m[j] = mm;
    rs[j] = rsqrtf(var + 1e-5f);
  }
  size_t total = (size_t)NN * DD / 4;
  size_t stride = (size_t)2048 * 256;
  for (size_t i = tid0; i < total; i += stride) {
    uint2 q = *((const uint2*)doutb + i);
    float4 v;
    v.x = (bu2f((u16)q.x) - m[0]) * rs[0];
    v.y = (bu2f((u16)(q.x >> 16)) - m[1]) * rs[1];
    v.z = (bu2f((u16)q.y) - m[2]) * rs[2];
    v.w = (bu2f((u16)(q.y >> 16)) - m[3]) * rs[3];
    *((float4*)out + i) = v;
  }
}

__global__ void k_fail(float* __restrict__ out, int n) {
  int i = blockIdx.x * 256 + threadIdx.x;
  if (i < n) out[i] = 1.0e6f;   // "workspace too small" marker
}

extern "C" void kernel_launch(void* const* d_in, const int* in_sizes, int n_in,
                              void* d_out, int out_size, void* d_ws, size_t ws_size,
                              hipStream_t stream) {
  (void)in_sizes; (void)n_in;
  const float* x      = (const float*)d_in[0];
  const float* rel    = (const float*)d_in[1];
  const int*   esrc   = (const int*)d_in[2];
  const int*   edst   = (const int*)d_in[3];
  const int*   etyp   = (const int*)d_in[4];
  const float* enorm  = (const float*)d_in[5];
  const float* in_w   = (const float*)d_in[6];
  const float* out_w  = (const float*)d_in[7];
  const float* loop_w = (const float*)d_in[8];
  const float* w_rel  = (const float*)d_in[9];
  const float* lr     = (const float*)d_in[10];
  const float* bias   = (const float*)d_in[11];
  float* dout = (float*)d_out;

  char* wsb = (char*)d_ws;
  size_t off = 0;
  u16* Apack = (u16*)(wsb + off); off += (size_t)NN * KP * 2;        // 122.9 MB
  u16* Bt    = (u16*)(wsb + off); off += (size_t)DD * KP * 2;        // 0.39 MB
  u16* xfh   = (u16*)(wsb + off); off += (size_t)NN * FD * 2;        // 41.0 MB
  u16* rfh   = (u16*)(wsb + off); off += (size_t)NR * FD * 2;        // 0.20 MB
  u16* Ft    = (u16*)(wsb + off); off += (size_t)DD * DD * 2;        // 0.13 MB
  u16* doutb = (u16*)(wsb + off); off += (size_t)NN * DD * 2;        // 41.0 MB
  uint2* recs = (uint2*)(wsb + off); off += (size_t)NE * 8;          // 6.4 MB
  float* sum1  = (float*)(wsb + off); off += DD * 4;                 // sum1,sum2,cnt
  float* sum2  = (float*)(wsb + off); off += DD * 4;                 //  contiguous ->
  int* cnt   = (int*)(wsb + off); off += (size_t)(NB + 1) * 4;       //  one memset
  int* baseA = (int*)(wsb + off); off += (size_t)(NB + 1) * 4;
  int* curA  = (int*)(wsb + off); off += (size_t)NB * 4;
  int* chT   = (int*)(wsb + off); off += 256 * 4;
  int* chO   = (int*)(wsb + off); off += 256 * 4;

  if (ws_size < off) {
    k_fail<<<(out_size + 255) / 256, 256, 0, stream>>>(dout, out_size);
    return;
  }

  hipMemsetAsync(sum1, 0, (2 * DD + NB + 1) * sizeof(int), stream);
  k_build<<<1024 + NE / 256, 256, 0, stream>>>(in_w, out_w, lr, loop_w, edst, cnt,
                                               Ft, Bt);
  k_scan1<<<NCH, 256, 0, stream>>>(cnt, baseA, chT);
  k_scan2<<<1, 256, 0, stream>>>(chT, chO);
  k_scan3<<<(NB + 255) / 256, 256, 0, stream>>>(baseA, chO, curA);
  k_scatter<<<NE / 256, 256, 0, stream>>>(esrc, edst, etyp, enorm, curA, recs);
  k_dft<<<(MT + 127) / 128, 512, 0, stream>>>(x, rel, Ft, xfh, rfh, Apack);
  k_reduce<<<NB / 4, 256, 0, stream>>>(xfh, rfh, recs, baseA, Apack);
  k_mgemm<<<NN / 128, 512, 0, stream>>>(Apack, Bt, bias, doutb, sum1, sum2);
  k_norm<<<2048 + NR, 256, 0, stream>>>(doutb, dout, sum1, sum2, rel, w_rel,
                                        dout + (size_t)NN * DD);
}

// Round 14
// 354.652 us; speedup vs baseline: 1.0390x; 1.0390x over previous
//
#include <hip/hip_runtime.h>

#define NN 80000     // nodes
#define NE 800000    // edges
#define EH 400000    // first half -> in_w
#define NR 400       // relations
#define DD 256       // feature dim
#define FD 256       // freq row: col0=bin0.re, col1=bin128.re, 2k/2k+1=bin k
#define KP 768       // GEMM K = 256*3 (in | out | self), = 12*64 exactly
#define NB 160000    // sort buckets: dir*NN + dst
#define NCH 157      // ceil(NB/1024) scan chunks
#define MT 80400     // total DFT rows (x + rel)
#define PI2 6.283185307179586f

typedef unsigned short u16;
typedef __attribute__((ext_vector_type(8))) short bf16x8;
typedef __attribute__((ext_vector_type(4))) float f32x4;
typedef __attribute__((ext_vector_type(2))) float f32x2;

static __device__ __forceinline__ float bu2f(u16 u) {
  return __uint_as_float(((unsigned int)u) << 16);
}
static __device__ __forceinline__ u16 f2bu(float f) {
  unsigned int x = __float_as_uint(f);
  x += 0x7fffu + ((x >> 16) & 1u);   // RNE
  return (u16)(x >> 16);
}
static __device__ __forceinline__ unsigned int pk2(float a, float b) {
  return (unsigned int)f2bu(a) | ((unsigned int)f2bu(b) << 16);
}
// async global->LDS 16B: lds dest = wave-uniform base + lane*16
static __device__ __forceinline__ void gload16(const void* g, void* l) {
  __builtin_amdgcn_global_load_lds(
      (const __attribute__((address_space(1))) unsigned int*)g,
      (__attribute__((address_space(3))) unsigned int*)l, 16, 0, 0);
}

// merged: blocks 0..255 Ft; 256..767 Bt in/out; 768..1023 Bt self; 1024+ hist
__global__ void k_build(const float* __restrict__ in_w, const float* __restrict__ out_w,
                        const float* __restrict__ lr, const float* __restrict__ loop_w,
                        const int* __restrict__ edst, int* __restrict__ cnt,
                        u16* __restrict__ Ft, u16* __restrict__ Bt) {
  __shared__ float L[DD];
  int bb = blockIdx.x, c = threadIdx.x;
  if (bb >= 1024) {                    // histogram branch
    int e = (bb - 1024) * 256 + c;
    int key = edst[e] + ((e >= EH) ? NN : 0);
    atomicAdd(&cnt[key], 1);
    return;
  }
  if (bb < 256) {
    int row = bb, j = c;
    int k, im;
    if (row == 0)      { k = 0;   im = 0; }
    else if (row == 1) { k = 128; im = 0; }
    else               { k = row >> 1; im = row & 1; }
    int m = (j * k) & 255;
    float th = -PI2 * (float)m * (1.0f / 256.0f);
    Ft[row * 256 + j] = f2bu(im ? sinf(th) : cosf(th));
  } else if (bb < 768) {
    int t = bb - 256;                  // 0..511
    const float* W = (t < 256) ? in_w : out_w;
    int tp = t & 255;
    int k, im; float alpha;
    if (tp == 0)      { k = 0;   im = 0; alpha = 1.0f; }
    else if (tp == 1) { k = 128; im = 0; alpha = 1.0f; }
    else              { k = tp >> 1; im = tp & 1; alpha = 2.0f; }
    float scale = alpha * (1.0f / 768.0f);
    int m = (c * k) & 255;
    float th = -PI2 * (float)m * (1.0f / 256.0f);
    L[c] = im ? sinf(th) : cosf(th);
    __syncthreads();
    float acc = 0.0f;
    for (int j = 0; j < DD; ++j)
      acc += L[j] * W[(size_t)j * DD + c];
    Bt[(size_t)c * KP + t] = f2bu(scale * acc);
  } else {
    int j = bb - 768;                  // 0..255
    L[c] = lr[c];
    __syncthreads();
    float acc = 0.0f;
    for (int k2 = 0; k2 < DD; ++k2)
      acc += L[(j + k2) & 255] * loop_w[(size_t)k2 * DD + c];
    Bt[(size_t)c * KP + 512 + j] = f2bu(acc * (1.0f / 3.0f));
  }
}

// MFMA DFT, N-fused 128x256: XF = [x;rel] @ Ft^T -> xfh/rfh (bf16, 512B rows)
__global__ __launch_bounds__(512) void k_dft(
    const float* __restrict__ x, const float* __restrict__ rel,
    const u16* __restrict__ Ft, u16* __restrict__ xfh, u16* __restrict__ rfh,
    u16* __restrict__ Ap) {
  __shared__ u16 sA[2][128 * 64];
  __shared__ u16 sB[256 * 64];
  int tid = threadIdx.x;
  int w = tid >> 6, lane = tid & 63;
  int r0 = blockIdx.x * 128;
  int wm = (w & 1) * 64, wn = (w >> 1) * 64;
  int fr = lane & 15, fg = lane >> 4;

  int arow = tid >> 2;                 // 0..127
  int acg = (tid & 3) * 16;            // 16 f32 per thread
  int gr = r0 + arow;
  int grc = gr < MT ? gr : MT - 1;
  const float* asrc = (grc < NN) ? (x + (size_t)grc * DD)
                                 : (rel + (size_t)(grc - NN) * DD);
  bool doAp = (gr < NN);

  float4 a0_, a1_, a2_, a3_;
#define LOADA(kb) { const float* p_ = asrc + (kb) * 64 + acg;                     \
    a0_ = *(const float4*)(p_);     a1_ = *(const float4*)(p_ + 4);               \
    a2_ = *(const float4*)(p_ + 8); a3_ = *(const float4*)(p_ + 12); }

#define STGB(kb) { _Pragma("unroll") for (int q = 0; q < 4; ++q) {                \
    int s_ = w * 4 + q; int c_ = 8 * s_ + (lane >> 3);                            \
    int cb_ = (lane & 7) ^ (c_ & 7);                                              \
    gload16(Ft + (size_t)c_ * 256 + (kb) * 64 + cb_ * 8, sB + s_ * 512); } }

#define CVTA(kb, buf) {                                                           \
    uint4 c0_ = make_uint4(pk2(a0_.x, a0_.y), pk2(a0_.z, a0_.w),                  \
                           pk2(a1_.x, a1_.y), pk2(a1_.z, a1_.w));                 \
    uint4 c1_ = make_uint4(pk2(a2_.x, a2_.y), pk2(a2_.z, a2_.w),                  \
                           pk2(a3_.x, a3_.y), pk2(a3_.z, a3_.w));                 \
    int b0_ = (tid & 3) * 2;                                                      \
    *(uint4*)(sA[buf] + arow * 64 + ((b0_ ^ (arow & 7)) * 8)) = c0_;              \
    *(uint4*)(sA[buf] + arow * 64 + (((b0_ + 1) ^ (arow & 7)) * 8)) = c1_;        \
    if (doAp) { u16* ap_ = Ap + (size_t)gr * KP + 512 + (kb) * 64 + acg;          \
      *(uint4*)(ap_) = c0_; *(uint4*)(ap_ + 8) = c1_; } }

  f32x4 acc[4][4];
#pragma unroll
  for (int i = 0; i < 4; ++i)
#pragma unroll
    for (int j = 0; j < 4; ++j) acc[i][j] = (f32x4){0.f, 0.f, 0.f, 0.f};

  LOADA(0)
  STGB(0)
  CVTA(0, 0)
  LOADA(1)
  __syncthreads();
  for (int kb = 0; kb < 4; ++kb) {
    int cur = kb & 1;
#pragma unroll
    for (int ks = 0; ks < 2; ++ks) {
      bf16x8 af[4], bfr[4];
#pragma unroll
      for (int mt = 0; mt < 4; ++mt) {
        int r = wm + mt * 16 + fr;
        af[mt] = *(const bf16x8*)(sA[cur] + r * 64 + ((ks * 32 + fg * 8) ^ ((r & 7) * 8)));
      }
#pragma unroll
      for (int nt = 0; nt < 4; ++nt) {
        int c = wn + nt * 16 + fr;
        bfr[nt] = *(const bf16x8*)(sB + c * 64 + ((ks * 32 + fg * 8) ^ ((c & 7) * 8)));
      }
#pragma unroll
      for (int mt = 0; mt < 4; ++mt)
#pragma unroll
        for (int nt = 0; nt < 4; ++nt)
          acc[mt][nt] = __builtin_amdgcn_mfma_f32_16x16x32_bf16(af[mt], bfr[nt],
                                                                acc[mt][nt], 0, 0, 0);
    }
    __syncthreads();
    if (kb < 3) {
      STGB(kb + 1)
      CVTA(kb + 1, cur ^ 1)
      if (kb < 2) LOADA(kb + 2)
      __syncthreads();
    }
  }
#undef LOADA
#undef STGB
#undef CVTA

#pragma unroll
  for (int mt = 0; mt < 4; ++mt)
#pragma unroll
    for (int nt = 0; nt < 4; ++nt) {
      int cg = wn + nt * 16 + fr;
#pragma unroll
      for (int j = 0; j < 4; ++j) {
        int rg = r0 + wm + mt * 16 + fg * 4 + j;
        u16 val = f2bu(acc[mt][nt][j]);
        if (rg < NN)      xfh[(size_t)rg * FD + cg] = val;
        else if (rg < MT) rfh[(size_t)(rg - NN) * FD + cg] = val;
      }
    }
}

__global__ __launch_bounds__(256) void k_scan1(const int* __restrict__ cnt,
                                               int* __restrict__ base,
                                               int* __restrict__ chunkTot) {
  __shared__ int wsum[4];
  int t = threadIdx.x;
  int g0 = blockIdx.x * 1024 + t * 4;
  int v[4], ex[4], s = 0;
#pragma unroll
  for (int j = 0; j < 4; ++j) v[j] = (g0 + j < NB) ? cnt[g0 + j] : 0;
#pragma unroll
  for (int j = 0; j < 4; ++j) { ex[j] = s; s += v[j]; }
  int lane = t & 63, w = t >> 6;
  int inc = s;
  for (int off = 1; off < 64; off <<= 1) {
    int n = __shfl_up(inc, off);
    if (lane >= off) inc += n;
  }
  if (lane == 63) wsum[w] = inc;
  __syncthreads();
  int woff = 0;
  for (int i = 0; i < w; ++i) woff += wsum[i];
  int exth = woff + inc - s;
#pragma unroll
  for (int j = 0; j < 4; ++j)
    if (g0 + j < NB) base[g0 + j] = exth + ex[j];
  if (t == 255) chunkTot[blockIdx.x] = woff + inc;
}

__global__ __launch_bounds__(256) void k_scan2(const int* __restrict__ chunkTot,
                                               int* __restrict__ chunkOff) {
  __shared__ int wsum[4];
  int t = threadIdx.x;
  int v = (t < NCH) ? chunkTot[t] : 0;
  int lane = t & 63, w = t >> 6;
  int inc = v;
  for (int off = 1; off < 64; off <<= 1) {
    int n = __shfl_up(inc, off);
    if (lane >= off) inc += n;
  }
  if (lane == 63) wsum[w] = inc;
  __syncthreads();
  int woff = 0;
  for (int i = 0; i < w; ++i) woff += wsum[i];
  if (t < NCH) chunkOff[t] = woff + inc - v;
}

__global__ void k_scan3(int* __restrict__ base, const int* __restrict__ chunkOff,
                        int* __restrict__ cursor) {
  int i = blockIdx.x * 256 + threadIdx.x;
  if (i < NB) {
    int b = base[i] + chunkOff[i >> 10];
    base[i] = b;
    cursor[i] = b;
  }
  if (i == 0) base[NB] = NE;
}

// scatter packed 8B records: {src | typ<<17, norm_bits} -> sorted position
__global__ void k_scatter(const int* __restrict__ esrc, const int* __restrict__ edst,
                          const int* __restrict__ etyp, const float* __restrict__ enorm,
                          int* __restrict__ cursor, uint2* __restrict__ recs) {
  int e = blockIdx.x * 256 + threadIdx.x;
  int key = edst[e] + ((e >= EH) ? NN : 0);
  int pos = atomicAdd(&cursor[key], 1);
  recs[pos] = make_uint2((unsigned int)esrc[e] | ((unsigned int)etyp[e] << 17),
                         __float_as_uint(enorm[e]));
}

// one wave per bucket, 4-edge ILP main loop + serial tail (R12-proven best).
// lane0 pair (cols 0,1) = two REAL bins: product is elementwise.
__global__ __launch_bounds__(256) void k_reduce(
    const u16* __restrict__ xfh, const u16* __restrict__ rfh,
    const uint2* __restrict__ recs, const int* __restrict__ base,
    u16* __restrict__ Ap) {
  int w = threadIdx.x >> 6, lane = threadIdx.x & 63;
  int b = blockIdx.x * 4 + w;
  int start = base[b], end = base[b + 1];
  bool l0 = (lane == 0);
  f32x2 a01 = (f32x2){0.f, 0.f}, a23 = (f32x2){0.f, 0.f};
  int p = start;
  for (; p + 3 < end; p += 4) {
    ushort4 xv[4], rv[4];
    float nm[4];
#pragma unroll
    for (int u = 0; u < 4; ++u) {
      uint2 rc = recs[p + u];
      nm[u] = __uint_as_float(rc.y);
      unsigned int s = rc.x & 0x1FFFFu, r = rc.x >> 17;
      xv[u] = *(const ushort4*)(xfh + (size_t)s * FD + 4 * lane);
      rv[u] = *(const ushort4*)(rfh + (size_t)r * FD + 4 * lane);
    }
#pragma unroll
    for (int u = 0; u < 4; ++u) {
      float xr0 = bu2f(xv[u].x), xi0 = bu2f(xv[u].y);
      float xr1 = bu2f(xv[u].z), xi1 = bu2f(xv[u].w);
      float rr0 = bu2f(rv[u].x), ri0 = bu2f(rv[u].y);
      float rr1 = bu2f(rv[u].z), ri1 = bu2f(rv[u].w);
      f32x2 tc = (f32x2){xr0, xr0} * (f32x2){rr0, ri0}
               + (f32x2){xi0, -xi0} * (f32x2){ri0, rr0};
      f32x2 te = (f32x2){xr0, xi0} * (f32x2){rr0, ri0};
      f32x2 t0 = l0 ? te : tc;
      a01 += t0 * nm[u];
      f32x2 t1 = (f32x2){xr1, xr1} * (f32x2){rr1, ri1}
               + (f32x2){xi1, -xi1} * (f32x2){ri1, rr1};
      a23 += t1 * nm[u];
    }
  }
  for (; p < end; ++p) {
    uint2 rc = recs[p];
    float nm0 = __uint_as_float(rc.y);
    unsigned int s = rc.x & 0x1FFFFu, r = rc.x >> 17;
    ushort4 xv0 = *(const ushort4*)(xfh + (size_t)s * FD + 4 * lane);
    ushort4 rv0 = *(const ushort4*)(rfh + (size_t)r * FD + 4 * lane);
    float xr0 = bu2f(xv0.x), xi0 = bu2f(xv0.y), xr1 = bu2f(xv0.z), xi1 = bu2f(xv0.w);
    float rr0 = bu2f(rv0.x), ri0 = bu2f(rv0.y), rr1 = bu2f(rv0.z), ri1 = bu2f(rv0.w);
    f32x2 tc = (f32x2){xr0, xr0} * (f32x2){rr0, ri0}
             + (f32x2){xi0, -xi0} * (f32x2){ri0, rr0};
    f32x2 te = (f32x2){xr0, xi0} * (f32x2){rr0, ri0};
    f32x2 t0 = l0 ? te : tc;
    a01 += t0 * nm0;
    f32x2 t1 = (f32x2){xr1, xr1} * (f32x2){rr1, ri1}
             + (f32x2){xi1, -xi1} * (f32x2){ri1, rr1};
    a23 += t1 * nm0;
  }
  u16* tp = Ap + ((b < NN) ? (size_t)b * KP : (size_t)(b - NN) * KP + 256);
  *(unsigned int*)(tp + 4 * lane)     = pk2(a01.x, a01.y);
  *(unsigned int*)(tp + 4 * lane + 2) = pk2(a23.x, a23.y);
}

// MFMA GEMM, N-fused 128x256: doutb(bf16) = Apack[80000][768] x Bt^T + bias
__global__ __launch_bounds__(512) void k_mgemm(
    const u16* __restrict__ Ap, const u16* __restrict__ Bt,
    const float* __restrict__ bias, u16* __restrict__ doutb,
    float* __restrict__ sum1, float* __restrict__ sum2) {
  __shared__ u16 sA[2][128 * 64];
  __shared__ u16 sB[256 * 64];
  int tid = threadIdx.x;
  int w = tid >> 6, lane = tid & 63;
  int r0 = blockIdx.x * 128;
  int wm = (w & 1) * 64, wn = (w >> 1) * 64;
  int fr = lane & 15, fg = lane >> 4;

#define STGA(kb, buf) { _Pragma("unroll") for (int q = 0; q < 2; ++q) {           \
    int s_ = w * 2 + q; int r_ = 8 * s_ + (lane >> 3);                            \
    int cb_ = (lane & 7) ^ (r_ & 7);                                              \
    gload16(Ap + (size_t)(r0 + r_) * KP + (kb) * 64 + cb_ * 8,                    \
            sA[buf] + s_ * 512); } }

#define STGB(kb) { _Pragma("unroll") for (int q = 0; q < 4; ++q) {                \
    int s_ = w * 4 + q; int c_ = 8 * s_ + (lane >> 3);                            \
    int cb_ = (lane & 7) ^ (c_ & 7);                                              \
    gload16(Bt + (size_t)c_ * KP + (kb) * 64 + cb_ * 8, sB + s_ * 512); } }

  f32x4 acc[4][4];
#pragma unroll
  for (int i = 0; i < 4; ++i)
#pragma unroll
    for (int j = 0; j < 4; ++j) acc[i][j] = (f32x4){0.f, 0.f, 0.f, 0.f};

  STGA(0, 0)
  STGB(0)
  __syncthreads();
  for (int kb = 0; kb < 12; ++kb) {
    int cur = kb & 1;
    if (kb < 11) STGA(kb + 1, cur ^ 1)
#pragma unroll
    for (int ks = 0; ks < 2; ++ks) {
      bf16x8 af[4], bfr[4];
#pragma unroll
      for (int mt = 0; mt < 4; ++mt) {
        int r = wm + mt * 16 + fr;
        af[mt] = *(const bf16x8*)(sA[cur] + r * 64 + ((ks * 32 + fg * 8) ^ ((r & 7) * 8)));
      }
#pragma unroll
      for (int nt = 0; nt < 4; ++nt) {
        int c = wn + nt * 16 + fr;
        bfr[nt] = *(const bf16x8*)(sB + c * 64 + ((ks * 32 + fg * 8) ^ ((c & 7) * 8)));
      }
#pragma unroll
      for (int mt = 0; mt < 4; ++mt)
#pragma unroll
        for (int nt = 0; nt < 4; ++nt)
          acc[mt][nt] = __builtin_amdgcn_mfma_f32_16x16x32_bf16(af[mt], bfr[nt],
                                                                acc[mt][nt], 0, 0, 0);
    }
    __syncthreads();
    if (kb < 11) { STGB(kb + 1) __syncthreads(); }
  }
#undef STGA
#undef STGB

  float s1[4] = {0.f, 0.f, 0.f, 0.f}, s2[4] = {0.f, 0.f, 0.f, 0.f};
#pragma unroll
  for (int nt = 0; nt < 4; ++nt) {
    int cg = wn + nt * 16 + fr;
    float bv = bias[cg];
#pragma unroll
    for (int mt = 0; mt < 4; ++mt) {
#pragma unroll
      for (int j = 0; j < 4; ++j) {
        int rg = r0 + wm + mt * 16 + fg * 4 + j;
        float val = acc[mt][nt][j] + bv;
        doutb[(size_t)rg * DD + cg] = f2bu(val);
        s1[nt] += val;
        s2[nt] += val * val;
      }
    }
  }
#pragma unroll
  for (int nt = 0; nt < 4; ++nt) {
    s1[nt] += __shfl_xor(s1[nt], 16); s1[nt] += __shfl_xor(s1[nt], 32);
    s2[nt] += __shfl_xor(s2[nt], 16); s2[nt] += __shfl_xor(s2[nt], 32);
  }
  if (lane < 16) {
#pragma unroll
    for (int nt = 0; nt < 4; ++nt) {
      atomicAdd(&sum1[wn + nt * 16 + lane], s1[nt]);
      atomicAdd(&sum2[wn + nt * 16 + lane], s2[nt]);
    }
  }
}

// merged: blocks 0..2047 normalize (bf16 in, f32 out); 2048.. rel GEMV
__global__ __launch_bounds__(256) void k_norm(const u16* __restrict__ doutb,
                                              float* __restrict__ out,
                                              const float* __restrict__ sum1,
                                              const float* __restrict__ sum2,
                                              const float* __restrict__ rel,
                                              const float* __restrict__ wrel,
                                              float* __restrict__ out2) {
  __shared__ float R[DD];
  int bb = blockIdx.x;
  if (bb >= 2048) {                    // rel branch
    int r = bb - 2048, c = threadIdx.x;
    R[c] = rel[(size_t)r * DD + c];
    __syncthreads();
    float acc = 0.0f;
    for (int j = 0; j < DD; ++j)
      acc += R[j] * wrel[(size_t)j * DD + c];
    out2[(size_t)r * DD + c] = acc;
    return;
  }
  size_t tid0 = (size_t)bb * 256 + threadIdx.x;
  int c0 = (int)((tid0 * 4) & 255);
  float m[4], rs[4];
#pragma unroll
  for (int j = 0; j < 4; ++j) {
    float mm = sum1[c0 + j] * (1.0f / (float)NN);
    float var = sum2[c0 + j] * (1.0f / (float)NN) - mm * mm;
    m[j] = mm;
    rs[j] = rsqrtf(var + 1e-5f);
  }
  size_t total = (size_t)NN * DD / 4;
  size_t stride = (size_t)2048 * 256;
  for (size_t i = tid0; i < total; i += stride) {
    uint2 q = *((const uint2*)doutb + i);
    float4 v;
    v.x = (bu2f((u16)q.x) - m[0]) * rs[0];
    v.y = (bu2f((u16)(q.x >> 16)) - m[1]) * rs[1];
    v.z = (bu2f((u16)q.y) - m[2]) * rs[2];
    v.w = (bu2f((u16)(q.y >> 16)) - m[3]) * rs[3];
    *((float4*)out + i) = v;
  }
}

__global__ void k_fail(float* __restrict__ out, int n) {
  int i = blockIdx.x * 256 + threadIdx.x;
  if (i < n) out[i] = 1.0e6f;   // "workspace too small" marker
}

extern "C" void kernel_launch(void* const* d_in, const int* in_sizes, int n_in,
                              void* d_out, int out_size, void* d_ws, size_t ws_size,
                              hipStream_t stream) {
  (void)in_sizes; (void)n_in;
  const float* x      = (const float*)d_in[0];
  const float* rel    = (const float*)d_in[1];
  const int*   esrc   = (const int*)d_in[2];
  const int*   edst   = (const int*)d_in[3];
  const int*   etyp   = (const int*)d_in[4];
  const float* enorm  = (const float*)d_in[5];
  const float* in_w   = (const float*)d_in[6];
  const float* out_w  = (const float*)d_in[7];
  const float* loop_w = (const float*)d_in[8];
  const float* w_rel  = (const float*)d_in[9];
  const float* lr     = (const float*)d_in[10];
  const float* bias   = (const float*)d_in[11];
  float* dout = (float*)d_out;

  char* wsb = (char*)d_ws;
  size_t off = 0;
  u16* Apack = (u16*)(wsb + off); off += (size_t)NN * KP * 2;        // 122.9 MB
  u16* Bt    = (u16*)(wsb + off); off += (size_t)DD * KP * 2;        // 0.39 MB
  u16* xfh   = (u16*)(wsb + off); off += (size_t)NN * FD * 2;        // 41.0 MB
  u16* rfh   = (u16*)(wsb + off); off += (size_t)NR * FD * 2;        // 0.20 MB
  u16* Ft    = (u16*)(wsb + off); off += (size_t)DD * DD * 2;        // 0.13 MB
  u16* doutb = (u16*)(wsb + off); off += (size_t)NN * DD * 2;        // 41.0 MB
  uint2* recs = (uint2*)(wsb + off); off += (size_t)NE * 8;          // 6.4 MB
  float* sum1  = (float*)(wsb + off); off += DD * 4;                 // sum1,sum2,cnt
  float* sum2  = (float*)(wsb + off); off += DD * 4;                 //  contiguous ->
  int* cnt   = (int*)(wsb + off); off += (size_t)(NB + 1) * 4;       //  one memset
  int* baseA = (int*)(wsb + off); off += (size_t)(NB + 1) * 4;
  int* curA  = (int*)(wsb + off); off += (size_t)NB * 4;
  int* chT   = (int*)(wsb + off); off += 256 * 4;
  int* chO   = (int*)(wsb + off); off += 256 * 4;

  if (ws_size < off) {
    k_fail<<<(out_size + 255) / 256, 256, 0, stream>>>(dout, out_size);
    return;
  }

  hipMemsetAsync(sum1, 0, (2 * DD + NB + 1) * sizeof(int), stream);
  k_build<<<1024 + NE / 256, 256, 0, stream>>>(in_w, out_w, lr, loop_w, edst, cnt,
                                               Ft, Bt);
  k_scan1<<<NCH, 256, 0, stream>>>(cnt, baseA, chT);
  k_scan2<<<1, 256, 0, stream>>>(chT, chO);
  k_scan3<<<(NB + 255) / 256, 256, 0, stream>>>(baseA, chO, curA);
  k_scatter<<<NE / 256, 256, 0, stream>>>(esrc, edst, etyp, enorm, curA, recs);
  k_dft<<<(MT + 127) / 128, 512, 0, stream>>>(x, rel, Ft, xfh, rfh, Apack);
  k_reduce<<<NB / 4, 256, 0, stream>>>(xfh, rfh, recs, baseA, Apack);
  k_mgemm<<<NN / 128, 512, 0, stream>>>(Apack, Bt, bias, doutb, sum1, sum2);
  k_norm<<<2048 + NR, 256, 0, stream>>>(doutb, dout, sum1, sum2, rel, w_rel,
                                        dout + (size_t)NN * DD);
}